// Round 14
// baseline (49.163 us; speedup 1.0000x reference)
//
#include <hip/hip_runtime.h>
#include <math.h>

#define N  2048
#define K  8
#define NK 1024
#define R  2             // rows per block
#define TPB 512
#define TAU_C 0.5f
#define TAU_S 0.5f

// Single fused kernel (replay-safe class, R8-R13). Block rebuilds index maps
// from immutable `idx` into LDS, then serves R=2 full output rows with DIRECT
// global gathers (no staging barriers -> waves run independently).
// Occupancy: grid 1024 = 4 blocks/CU, LDS 33KB = 4 blocks/CU, VGPR<=64
// -> up to 32 waves/CU, all blocks resident in one round (scan wall-time flat).
__global__ void __launch_bounds__(TPB, 8)
fia_fused(const float* __restrict__ adj,
          const int*   __restrict__ idx,
          float* __restrict__ out) {
    __shared__ short jj[K][N];          // 32 KB: pos of y in idx[k], or -1
    __shared__ short ixs[K][R];         // pos of row x in idx[k], or -1
    __shared__ float lutCS[81];         // exact IEEE cs/n for all (cnt,cs)

    const int tid = threadIdx.x;
    const int X0  = blockIdx.x * R;

    // ---- one-time init: maps to -1, C-LUT (exact IEEE divides)
    {
        int4  m1 = make_int4(-1, -1, -1, -1);
        int4* p4 = (int4*)&jj[0][0];                 // K*N*2/16 = 2048 int4
        #pragma unroll
        for (int q = 0; q < (K * N * 2) / (16 * TPB); ++q)   // 4
            p4[q * TPB + tid] = m1;
        if (tid < K * R) ((short*)ixs)[tid] = (short)-1;
        if (tid < 81) {
            int cn = tid / 9, cc = tid % 9;
            lutCS[tid] = (float)cc / fmaxf((float)cn, 1e-5f);  // IEEE divide
        }
    }
    __syncthreads();

    // ---- scan idx (8192 entries, coalesced, L2-hot). Unique writer per cell.
    #pragma unroll
    for (int it = 0; it < (K * NK) / TPB; ++it) {    // 16
        int t   = it * TPB + tid;
        int val = idx[t];                            // coalesced
        int k   = t >> 10;                           // constant per iteration
        int p   = t & (NK - 1);
        jj[k][val] = (short)p;
        int rel = val - X0;
        if ((unsigned)rel < (unsigned)R) ixs[k][rel] = (short)p;
    }
    __syncthreads();

    // ---- hoisted per-thread column state (reused by both rows)
    const int y0 = tid * 4;                          // 4 consecutive columns
    int jc[K][4];                                    // clamped j
    int jmask[4] = {0, 0, 0, 0};
    #pragma unroll
    for (int k = 0; k < K; ++k) {
        short4 v = *(const short4*)&jj[k][y0];       // ds_read_b64
        int j0 = v.x, j1 = v.y, j2 = v.z, j3 = v.w;
        jmask[0] |= (j0 >= 0) ? (1 << k) : 0;
        jmask[1] |= (j1 >= 0) ? (1 << k) : 0;
        jmask[2] |= (j2 >= 0) ? (1 << k) : 0;
        jmask[3] |= (j3 >= 0) ? (1 << k) : 0;
        jc[k][0] = j0 & ~(j0 >> 31);                 // max(j,0)
        jc[k][1] = j1 & ~(j1 >> 31);
        jc[k][2] = j2 & ~(j2 >> 31);
        jc[k][3] = j3 & ~(j3 >> 31);
    }

    // ---- row loop: direct gathers, no barriers -> waves independent.
    #pragma unroll 1
    for (int r = 0; r < R; ++r) {
        int kp = 0;
        int ixr[K];
        #pragma unroll
        for (int k = 0; k < K; ++k) {
            int v = (int)ixs[k][r];                  // uniform LDS read
            ixr[k] = __builtin_amdgcn_readfirstlane(v);
            kp |= (ixr[k] >= 0) ? (1 << k) : 0;
        }

        // gathers + first-pass sums, scalar-gated per k (skip absent clients)
        float vraw[4][K];                            // only present-k cells used
        float sum[4] = {0.f, 0.f, 0.f, 0.f};
        int   csi[4] = {0, 0, 0, 0};
        #pragma unroll
        for (int k = 0; k < K; ++k) {
            if ((kp >> k) & 1) {                     // SGPR branch
                const float* __restrict__ bk =
                    adj + ((size_t)k * NK + (size_t)ixr[k]) * NK;
                #pragma unroll
                for (int yy = 0; yy < 4; ++yy) {
                    bool  p = (jmask[yy] >> k) & 1;
                    float a = bk[jc[k][yy]];         // consecutive-j gather
                    a = p ? a : 0.f;                 // exact a*mask
                    vraw[yy][k] = a;
                    sum[yy] += a;                    // +0.0 for absent == ref
                    csi[yy] += (a > TAU_C) ? 1 : 0;  // absent a=0 -> false
                }
            }
        }

        // second pass + epilogue: exact reference rounding sequence.
        float res[4];
        #pragma unroll
        for (int yy = 0; yy < 4; ++yy) {
            const int m   = jmask[yy] & kp;
            const int cnt = __popc(m);
            float n    = fmaxf((float)cnt, 1e-5f);
            float mean = sum[yy] / n;                // IEEE divide

            float vs = 0.f;
            #pragma unroll
            for (int k = 0; k < K; ++k) {
                if ((kp >> k) & 1) {                 // SGPR branch
                    bool  p = (m >> k) & 1;
                    float d = vraw[yy][k] - mean;
                    vs += p ? d * d : 0.f;           // select blocks fma-fuse
                }
            }
            float C = lutCS[cnt * 9 + csi[yy]];      // == cs/n, same IEEE bits
            float V = vs / n;                        // IEEE divide
            float S = C * expf(-V);                  // precise expf
            float rr = (S > TAU_S) ? mean : 0.f;
            res[yy] = (cnt > 0) ? rr : 0.f;
        }

        float4 o;
        o.x = res[0]; o.y = res[1]; o.z = res[2]; o.w = res[3];
        *(float4*)(out + (size_t)(X0 + r) * N + y0) = o;
    }
}

extern "C" void kernel_launch(void* const* d_in, const int* in_sizes, int n_in,
                              void* d_out, int out_size, void* d_ws, size_t ws_size,
                              hipStream_t stream) {
    const float* adj = (const float*)d_in[0];        // (K, NK, NK) f32
    const int*   idx = (const int*)d_in[1];          // (K, NK) i32
    float*       out = (float*)d_out;                // (N, N) f32

    dim3 block(TPB, 1, 1);
    dim3 grid(N / R, 1, 1);                          // 1024 blocks x 2 rows
    fia_fused<<<grid, block, 0, stream>>>(adj, idx, out);
}

// Round 15
// 35.575 us; speedup vs baseline: 1.3819x; 1.3819x over previous
//
#include <hip/hip_runtime.h>
#include <math.h>

#define N  2048
#define K  8
#define NK 1024
#define R  2             // rows per block
#define TPB 512
#define TAU_C 0.5f
#define TAU_S 0.5f

// Single fused kernel (replay-safe class, R8-R14). Block rebuilds index maps
// from immutable `idx` into LDS, then serves R=2 full output rows with DIRECT
// global gathers (no staging barriers -> waves run independently).
// R15 = R14 with launch_bounds(512,4): R14's (512,8) forced VGPR=32 + scratch
// spill (WRITE 95MB) which destroyed it. Cap 128 -> expect 64 (R9 precedent),
// giving 4 blocks/CU (grid & LDS) x 8 waves = 32 waves/CU, spill-free.
__global__ void __launch_bounds__(TPB, 4)
fia_fused(const float* __restrict__ adj,
          const int*   __restrict__ idx,
          float* __restrict__ out) {
    __shared__ short jj[K][N];          // 32 KB: pos of y in idx[k], or -1
    __shared__ short ixs[K][R];         // pos of row x in idx[k], or -1
    __shared__ float lutCS[81];         // exact IEEE cs/n for all (cnt,cs)

    const int tid = threadIdx.x;
    const int X0  = blockIdx.x * R;

    // ---- one-time init: maps to -1, C-LUT (exact IEEE divides)
    {
        int4  m1 = make_int4(-1, -1, -1, -1);
        int4* p4 = (int4*)&jj[0][0];                 // K*N*2/16 = 2048 int4
        #pragma unroll
        for (int q = 0; q < (K * N * 2) / (16 * TPB); ++q)   // 4
            p4[q * TPB + tid] = m1;
        if (tid < K * R) ((short*)ixs)[tid] = (short)-1;
        if (tid < 81) {
            int cn = tid / 9, cc = tid % 9;
            lutCS[tid] = (float)cc / fmaxf((float)cn, 1e-5f);  // IEEE divide
        }
    }
    __syncthreads();

    // ---- scan idx (8192 entries, coalesced, L2-hot). Unique writer per cell.
    #pragma unroll
    for (int it = 0; it < (K * NK) / TPB; ++it) {    // 16
        int t   = it * TPB + tid;
        int val = idx[t];                            // coalesced
        int k   = t >> 10;                           // constant per iteration
        int p   = t & (NK - 1);
        jj[k][val] = (short)p;
        int rel = val - X0;
        if ((unsigned)rel < (unsigned)R) ixs[k][rel] = (short)p;
    }
    __syncthreads();

    // ---- hoisted per-thread column state (reused by both rows)
    const int y0 = tid * 4;                          // 4 consecutive columns
    int jc[K][4];                                    // clamped j
    int jmask[4] = {0, 0, 0, 0};
    #pragma unroll
    for (int k = 0; k < K; ++k) {
        short4 v = *(const short4*)&jj[k][y0];       // ds_read_b64
        int j0 = v.x, j1 = v.y, j2 = v.z, j3 = v.w;
        jmask[0] |= (j0 >= 0) ? (1 << k) : 0;
        jmask[1] |= (j1 >= 0) ? (1 << k) : 0;
        jmask[2] |= (j2 >= 0) ? (1 << k) : 0;
        jmask[3] |= (j3 >= 0) ? (1 << k) : 0;
        jc[k][0] = j0 & ~(j0 >> 31);                 // max(j,0)
        jc[k][1] = j1 & ~(j1 >> 31);
        jc[k][2] = j2 & ~(j2 >> 31);
        jc[k][3] = j3 & ~(j3 >> 31);
    }

    // ---- row loop: direct gathers, no barriers -> waves independent.
    #pragma unroll 1
    for (int r = 0; r < R; ++r) {
        int kp = 0;
        int ixr[K];
        #pragma unroll
        for (int k = 0; k < K; ++k) {
            int v = (int)ixs[k][r];                  // uniform LDS read
            ixr[k] = __builtin_amdgcn_readfirstlane(v);
            kp |= (ixr[k] >= 0) ? (1 << k) : 0;
        }

        // gathers + first-pass sums, scalar-gated per k (skip absent clients)
        float vraw[4][K];                            // only present-k cells used
        float sum[4] = {0.f, 0.f, 0.f, 0.f};
        int   csi[4] = {0, 0, 0, 0};
        #pragma unroll
        for (int k = 0; k < K; ++k) {
            if ((kp >> k) & 1) {                     // SGPR branch
                const float* __restrict__ bk =
                    adj + ((size_t)k * NK + (size_t)ixr[k]) * NK;
                #pragma unroll
                for (int yy = 0; yy < 4; ++yy) {
                    bool  p = (jmask[yy] >> k) & 1;
                    float a = bk[jc[k][yy]];         // consecutive-j gather
                    a = p ? a : 0.f;                 // exact a*mask
                    vraw[yy][k] = a;
                    sum[yy] += a;                    // +0.0 for absent == ref
                    csi[yy] += (a > TAU_C) ? 1 : 0;  // absent a=0 -> false
                }
            }
        }

        // second pass + epilogue: exact reference rounding sequence.
        float res[4];
        #pragma unroll
        for (int yy = 0; yy < 4; ++yy) {
            const int m   = jmask[yy] & kp;
            const int cnt = __popc(m);
            float n    = fmaxf((float)cnt, 1e-5f);
            float mean = sum[yy] / n;                // IEEE divide

            float vs = 0.f;
            #pragma unroll
            for (int k = 0; k < K; ++k) {
                if ((kp >> k) & 1) {                 // SGPR branch
                    bool  p = (m >> k) & 1;
                    float d = vraw[yy][k] - mean;
                    vs += p ? d * d : 0.f;           // select blocks fma-fuse
                }
            }
            float C = lutCS[cnt * 9 + csi[yy]];      // == cs/n, same IEEE bits
            float V = vs / n;                        // IEEE divide
            float S = C * expf(-V);                  // precise expf
            float rr = (S > TAU_S) ? mean : 0.f;
            res[yy] = (cnt > 0) ? rr : 0.f;
        }

        float4 o;
        o.x = res[0]; o.y = res[1]; o.z = res[2]; o.w = res[3];
        *(float4*)(out + (size_t)(X0 + r) * N + y0) = o;
    }
}

extern "C" void kernel_launch(void* const* d_in, const int* in_sizes, int n_in,
                              void* d_out, int out_size, void* d_ws, size_t ws_size,
                              hipStream_t stream) {
    const float* adj = (const float*)d_in[0];        // (K, NK, NK) f32
    const int*   idx = (const int*)d_in[1];          // (K, NK) i32
    float*       out = (float*)d_out;                // (N, N) f32

    dim3 block(TPB, 1, 1);
    dim3 grid(N / R, 1, 1);                          // 1024 blocks x 2 rows
    fia_fused<<<grid, block, 0, stream>>>(adj, idx, out);
}

// Round 16
// 22.277 us; speedup vs baseline: 2.2068x; 1.5969x over previous
//
#include <hip/hip_runtime.h>
#include <math.h>

#define N  2048
#define K  8
#define NK 1024
#define R  4             // rows per block
#define TPB 512
#define SLOT NK          // zero slot index in stage rows
#define TAU_C 0.5f
#define TAU_S 0.5f

// Single fused kernel (replay-safe class, R8-R15). R13 structure (best: 27.6us)
// + two changes:
//  (1) int4-vectorized idx scan (16 -> 4 iters)
//  (2) S>0.5 decision via precomputed conservative bounds on vs (no V-divide,
//      no expf) -- in-band cells (~0.1%, margin 1000x error bound) fall back to
//      the byte-exact reference sequence, so decisions are provably identical.
__global__ void __launch_bounds__(TPB, 4)
fia_fused(const float* __restrict__ adj,
          const int*   __restrict__ idx,
          float* __restrict__ out) {
    __shared__ short  jj[K][N];          // 32 KB: pos of y in idx[k], or -1
    __shared__ short  ixs[K][R];         // pos of row x in idx[k], or -1
    __shared__ float  stage[K][NK + 4];  // 32.9 KB: row data + zero slot
    __shared__ float  lutCS[81];         // exact IEEE cs/n (ref C bits)
    __shared__ float2 lutB[81];          // (BloN, BhiN) decision bounds on vs

    const int tid = threadIdx.x;
    const int X0  = blockIdx.x * R;

    // ---- one-time init: maps to -1, zero slots, decision LUTs
    {
        int4  m1 = make_int4(-1, -1, -1, -1);
        int4* p4 = (int4*)&jj[0][0];                 // 2048 int4
        #pragma unroll
        for (int q = 0; q < (K * N * 2) / (16 * TPB); ++q)   // 4
            p4[q * TPB + tid] = m1;
        if (tid < K * R) ((short*)ixs)[tid] = (short)-1;
        if (tid < K) stage[tid][SLOT] = 0.0f;        // zero slot per client
        if (tid < 81) {
            int cn = tid / 9, cc = tid % 9;
            float nn = fmaxf((float)cn, 1e-5f);
            float C  = (float)cc / nn;               // IEEE divide == ref C bits
            lutCS[tid] = C;
            float lo, hi;
            if (2 * cc <= cn) {                      // C<=0.5 -> S<=0.5 always
                lo = -2.0f; hi = -1.0f;              // vs>=0>hi -> reject
            } else {
                float B = logf(2.0f * C);            // ~V boundary: S=0.5
                float d = 1e-3f * (1.0f + fabsf(B)); // >=1000x all err sources
                lo = (B - d) * (float)cn;            // bounds in vs-space
                hi = (B + d) * (float)cn;
            }
            lutB[tid] = make_float2(lo, hi);
        }
    }
    __syncthreads();

    // ---- scan idx: int4 loads (2048 int4, coalesced). base%4==0 and
    // 1024%4==0 -> all 4 elements share k. Unique writer per cell.
    #pragma unroll
    for (int it = 0; it < (K * NK) / (4 * TPB); ++it) {      // 4
        int  t4   = it * TPB + tid;
        int4 w    = ((const int4*)idx)[t4];          // coalesced 16B
        int  base = t4 * 4;
        int  k    = base >> 10;
        int  p    = base & (NK - 1);
        jj[k][w.x] = (short)(p);
        jj[k][w.y] = (short)(p + 1);
        jj[k][w.z] = (short)(p + 2);
        jj[k][w.w] = (short)(p + 3);
        int r0 = w.x - X0, r1 = w.y - X0, r2 = w.z - X0, r3 = w.w - X0;
        if ((unsigned)r0 < (unsigned)R) ixs[k][r0] = (short)(p);
        if ((unsigned)r1 < (unsigned)R) ixs[k][r1] = (short)(p + 1);
        if ((unsigned)r2 < (unsigned)R) ixs[k][r2] = (short)(p + 2);
        if ((unsigned)r3 < (unsigned)R) ixs[k][r3] = (short)(p + 3);
    }
    __syncthreads();

    // ---- hoisted per-thread column state (reused by all R rows)
    const int y0 = tid * 4;                          // 4 consecutive columns
    int jc[K][4];                                    // gather index or SLOT
    int jmask[4] = {0, 0, 0, 0};
    #pragma unroll
    for (int k = 0; k < K; ++k) {
        short4 v = *(const short4*)&jj[k][y0];       // ds_read_b64
        int j0 = v.x, j1 = v.y, j2 = v.z, j3 = v.w;
        jmask[0] |= (j0 >= 0) ? (1 << k) : 0;
        jmask[1] |= (j1 >= 0) ? (1 << k) : 0;
        jmask[2] |= (j2 >= 0) ? (1 << k) : 0;
        jmask[3] |= (j3 >= 0) ? (1 << k) : 0;
        jc[k][0] = (j0 >= 0) ? j0 : SLOT;            // absent -> zero slot
        jc[k][1] = (j1 >= 0) ? j1 : SLOT;
        jc[k][2] = (j2 >= 0) ? j2 : SLOT;
        jc[k][3] = (j3 >= 0) ? j3 : SLOT;
    }

    // ---- row loop (R13-proven staging schedule)
    #pragma unroll 1
    for (int r = 0; r < R; ++r) {
        int kp = 0;
        int ixr[K];
        #pragma unroll
        for (int k = 0; k < K; ++k) {
            int v = (int)ixs[k][r];                  // uniform LDS read
            ixr[k] = __builtin_amdgcn_readfirstlane(v);
            kp |= (ixr[k] >= 0) ? (1 << k) : 0;
        }

        // STAGE loads first (overlap with prev row's stats in other waves)
        float2 sr[K];
        #pragma unroll
        for (int k = 0; k < K; ++k) {
            if (ixr[k] >= 0) {                       // scalar branch
                const float2* __restrict__ src =
                    (const float2*)(adj + ((size_t)k * NK + (size_t)ixr[k]) * NK);
                sr[k] = src[tid];                    // fully coalesced 8B
            }
        }
        __syncthreads();                             // WAR: prev row done w/ stage
        #pragma unroll
        for (int k = 0; k < K; ++k) {
            if (ixr[k] >= 0)
                ((float2*)&stage[k][0])[tid] = sr[k];   // ds_write_b64
        }
        __syncthreads();                             // stage visible

        // PASS A: gather + sum + cs, scalar-gated; select-free (zero slot).
        float vraw[4][K];                            // only present-k cells used
        float sum[4] = {0.f, 0.f, 0.f, 0.f};
        int   csi[4] = {0, 0, 0, 0};
        #pragma unroll
        for (int k = 0; k < K; ++k) {
            if ((kp >> k) & 1) {                     // SGPR branch
                #pragma unroll
                for (int yy = 0; yy < 4; ++yy) {
                    float a = stage[k][jc[k][yy]];   // ds_read_b32
                    vraw[yy][k] = a;
                    sum[yy] += a;                    // +0.0 for absent == ref
                    csi[yy] += (a > TAU_C) ? 1 : 0;  // absent a=0 -> false
                }
            }
        }

        // PASS B + epilogue: mean (exact), vs (exact), bounds decision.
        float res[4];
        #pragma unroll
        for (int yy = 0; yy < 4; ++yy) {
            const int m   = jmask[yy] & kp;
            const int cnt = __popc(m);
            float n    = fmaxf((float)cnt, 1e-5f);
            float mean = sum[yy] / n;                // IEEE divide (ref bits)

            float vs = 0.f;
            #pragma unroll
            for (int k = 0; k < K; ++k) {
                if ((kp >> k) & 1) {                 // SGPR branch
                    bool  p = (m >> k) & 1;
                    float d = vraw[yy][k] - mean;
                    vs += p ? d * d : 0.f;           // select blocks fma-fuse
                }
            }

            const int li = cnt * 9 + csi[yy];
            float2 bb = lutB[li];
            bool acc;
            if (__builtin_expect(vs >= bb.x && vs <= bb.y, 0)) {
                // in-band (~0.1%): byte-exact reference sequence
                float C = lutCS[li];                 // == cs/n, same IEEE bits
                float V = vs / n;                    // IEEE divide
                float S = C * expf(-V);              // precise expf
                acc = (S > TAU_S);
            } else {
                acc = (vs < bb.x);                   // certain accept / reject
            }
            res[yy] = acc ? mean : 0.f;              // cnt==0 -> reject -> 0
        }

        float4 o;
        o.x = res[0]; o.y = res[1]; o.z = res[2]; o.w = res[3];
        *(float4*)(out + (size_t)(X0 + r) * N + y0) = o;
    }
}

extern "C" void kernel_launch(void* const* d_in, const int* in_sizes, int n_in,
                              void* d_out, int out_size, void* d_ws, size_t ws_size,
                              hipStream_t stream) {
    const float* adj = (const float*)d_in[0];        // (K, NK, NK) f32
    const int*   idx = (const int*)d_in[1];          // (K, NK) i32
    float*       out = (float*)d_out;                // (N, N) f32

    dim3 block(TPB, 1, 1);
    dim3 grid(N / R, 1, 1);                          // 512 blocks x 4 rows
    fia_fused<<<grid, block, 0, stream>>>(adj, idx, out);
}